// Round 5
// baseline (239.037 us; speedup 1.0000x reference)
//
#include <hip/hip_runtime.h>

// EMA chunked scan + inverse-gather broadcast for DeChunkLayer (R5).
//
// x: (1, 16384, 1024) f32, p_selected: (16384,) f32, b: (1, 32768) i32
// out: (1, 32768, 1024) f32
// z_t = (1-p_t) z_{t-1} + p_t x_t  (p clipped to [1e-4, 1-1e-4])
// out[f] = z[t] for f in [pos[t], pos[t+1])
//
// R5 structure (3 plain kernels; coop launch fails in this harness):
//  K1  chunk_kernel      : per-chunk local scan -> Bbuf/Abuf; b segment sums.
//  K1.5 interchunk_kernel: tiny (4 blocks) serial scan over 512 chunk
//                          aggregates -> Hbuf (state before each chunk).
//                          Replaces R4's redundant per-block replay, which
//                          generated ~512 MiB of L2 traffic inside K2.
//  K2  dechunk_kernel    : pos rank-select + final chunk scan (h from Hbuf)
//                          + ranged broadcast writes. Nontemporal x loads /
//                          out stores to stop L2 write-allocate thrash.

#define DCH 1024
#define L_COMP 16384
#define L_FULL 32768
#define CHUNK 32
#define NCHUNK (L_COMP / CHUNK)   // 512
#define SEG (L_FULL / NCHUNK)     // 64 b-elements per block
#define EPSV 1e-4f

typedef float v4f __attribute__((ext_vector_type(4)));

__device__ __forceinline__ float clipp(float p) {
    p = fmaxf(p, EPSV);
    p = fminf(p, 1.0f - EPSV);
    return p;
}

// ---- K1: chunk-local scan (zero init) -> Bbuf[c], Abuf[c]; b segment sums
__global__ __launch_bounds__(256, 2) void chunk_kernel(
    const float* __restrict__ x, const float* __restrict__ p,
    const int* __restrict__ b,
    float* __restrict__ Bbuf, float* __restrict__ Abuf, int* __restrict__ bsum) {
    const int c = blockIdx.x;
    const int tid = threadIdx.x;
    const int lane = tid & 63;
    const int wave = tid >> 6;
    const int base = c * CHUNK;

    const v4f* x4 = reinterpret_cast<const v4f*>(x) + (size_t)c * CHUNK * (DCH / 4) + tid;
    v4f h = (v4f)0.f;
    float aprod = 1.0f;
    for (int ib = 0; ib < CHUNK; ib += 8) {
        v4f xv[8];
        float pv[8];
#pragma unroll
        for (int j = 0; j < 8; ++j) {
            xv[j] = x4[(ib + j) * (DCH / 4)];
            pv[j] = clipp(p[base + ib + j]); // uniform -> scalar load
        }
#pragma unroll
        for (int j = 0; j < 8; ++j) {
            float a = 1.0f - pv[j];
            h = a * h + pv[j] * xv[j];
            aprod *= a;
        }
    }
    reinterpret_cast<v4f*>(Bbuf)[c * (DCH / 4) + tid] = h;
    if (tid == 0) Abuf[c] = aprod;
    if (wave == 0) {
        int v = b[c * SEG + lane];
        int s = v;
#pragma unroll
        for (int off = 1; off < 64; off <<= 1) s += __shfl_xor(s, off, 64);
        if (lane == 0) bsum[c] = s;
    }
}

// ---- K1.5: serial inter-chunk scan; Hbuf[k][ch] = state BEFORE chunk k.
// 4 blocks x 64 threads, 4 channels/thread. Bbuf is L2-resident (2 MiB).
#define BATCHB 32
__global__ __launch_bounds__(64) void interchunk_kernel(
    const float* __restrict__ Bbuf, const float* __restrict__ Abuf,
    float* __restrict__ Hbuf) {
    const int ch4 = blockIdx.x * 64 + threadIdx.x; // float4 channel group
    const v4f* B4 = reinterpret_cast<const v4f*>(Bbuf) + ch4;
    v4f* H4 = reinterpret_cast<v4f*>(Hbuf) + ch4;
    v4f h = (v4f)0.f;
    for (int cb = 0; cb < NCHUNK; cb += BATCHB) {
        v4f bv[BATCHB];
        float av[BATCHB];
#pragma unroll
        for (int j = 0; j < BATCHB; ++j) {
            bv[j] = B4[(cb + j) * (DCH / 4)];
            av[j] = Abuf[cb + j]; // uniform -> scalar load
        }
#pragma unroll
        for (int j = 0; j < BATCHB; ++j) {
            H4[(cb + j) * (DCH / 4)] = h;
            h = av[j] * h + bv[j];
        }
    }
}

// ---- K2: pos rank-select + final chunk scan + ranged broadcast writes
__global__ __launch_bounds__(256, 2) void dechunk_kernel(
    const float* __restrict__ x, const float* __restrict__ p,
    const int* __restrict__ b, float* __restrict__ out,
    const float* __restrict__ Hbuf, const int* __restrict__ bsum) {
    const int c = blockIdx.x;
    const int tid = threadIdx.x;
    const int lane = tid & 63;
    const int wave = tid >> 6;
    const int base = c * CHUNK;

    __shared__ int bpref[NCHUNK + 1];
    __shared__ int spos[CHUNK + 1];
    __shared__ int wtot[4];

    // (a) block-local exclusive prefix over the 512 segment sums
    {
        int v0 = bsum[2 * tid];
        int v1 = bsum[2 * tid + 1];
        int s = v0 + v1;
        int incl = s;
#pragma unroll
        for (int off = 1; off < 64; off <<= 1) {
            int n = __shfl_up(incl, off, 64);
            if (lane >= off) incl += n;
        }
        if (lane == 63) wtot[wave] = incl;
        __syncthreads();
        int woff = 0;
        for (int w = 0; w < wave; ++w) woff += wtot[w];
        int ex = woff + incl - s; // exclusive prefix of this thread's pair
        bpref[2 * tid] = ex;
        bpref[2 * tid + 1] = ex + v0;
        if (tid == 0) bpref[NCHUNK] = L_COMP;
        __syncthreads();
    }

    // (b) rank-select this chunk's 33 pos values (threads 0..32)
    if (tid <= CHUNK) {
        int t = base + tid; // global one-rank (0-indexed)
        int posv = L_FULL;
        if (t < L_COMP) {
            int lo = 0, hi = NCHUNK;
            while (hi - lo > 1) {
                int mid = (lo + hi) >> 1;
                if (bpref[mid] <= t) lo = mid; else hi = mid;
            }
            int lr = t - bpref[lo]; // local rank within segment lo
            const int4* bseg = reinterpret_cast<const int4*>(b) + lo * (SEG / 4);
            int cnt = 0;
#pragma unroll 4
            for (int q = 0; q < SEG / 4; ++q) {
                int4 w = bseg[q];
                if (w.x) { if (cnt == lr) posv = lo * SEG + 4 * q + 0; ++cnt; }
                if (w.y) { if (cnt == lr) posv = lo * SEG + 4 * q + 1; ++cnt; }
                if (w.z) { if (cnt == lr) posv = lo * SEG + 4 * q + 2; ++cnt; }
                if (w.w) { if (cnt == lr) posv = lo * SEG + 4 * q + 3; ++cnt; }
            }
        }
        spos[tid] = posv;
    }
    __syncthreads();

    // (c) final scan of chunk c with true init; broadcast-write output ranges.
    // x is single-use (nt load); out is write-once (nt store) — keep L2 for
    // Bbuf/Hbuf/bsum instead of 128 MiB of write-allocates.
    {
        const v4f* x4 = reinterpret_cast<const v4f*>(x) + (size_t)c * CHUNK * (DCH / 4) + tid;
        v4f* out4 = reinterpret_cast<v4f*>(out) + tid;
        v4f h = reinterpret_cast<const v4f*>(Hbuf)[c * (DCH / 4) + tid];
        int f0 = spos[0];
        for (int ib = 0; ib < CHUNK; ib += 8) {
            v4f xv[8];
            float pv[8];
            int fe[8];
#pragma unroll
            for (int j = 0; j < 8; ++j) {
                xv[j] = __builtin_nontemporal_load(&x4[(ib + j) * (DCH / 4)]);
                pv[j] = clipp(p[base + ib + j]); // uniform -> scalar
                fe[j] = spos[ib + j + 1];        // LDS
            }
#pragma unroll
            for (int j = 0; j < 8; ++j) {
                float a = 1.0f - pv[j];
                h = a * h + pv[j] * xv[j];
                for (int f = f0; f < fe[j]; ++f) {
                    __builtin_nontemporal_store(h, &out4[(size_t)f * (DCH / 4)]);
                }
                f0 = fe[j];
            }
        }
    }
}

extern "C" void kernel_launch(void* const* d_in, const int* in_sizes, int n_in,
                              void* d_out, int out_size, void* d_ws, size_t ws_size,
                              hipStream_t stream) {
    const float* x = (const float*)d_in[0];
    const float* p = (const float*)d_in[1];
    const int* b = (const int*)d_in[2];
    float* out = (float*)d_out;

    char* ws = (char*)d_ws;
    float* Abuf = (float*)ws;                  // NCHUNK floats (2 KiB)
    int* bsum = (int*)(ws + 4096);             // NCHUNK ints (2 KiB)
    float* Bbuf = (float*)(ws + 8192);         // NCHUNK*DCH floats (2 MiB), 16B aligned
    float* Hbuf = Bbuf + (size_t)NCHUNK * DCH; // NCHUNK*DCH floats (2 MiB)

    chunk_kernel<<<NCHUNK, 256, 0, stream>>>(x, p, b, Bbuf, Abuf, bsum);
    interchunk_kernel<<<4, 64, 0, stream>>>(Bbuf, Abuf, Hbuf);
    dechunk_kernel<<<NCHUNK, 256, 0, stream>>>(x, p, b, out, Hbuf, bsum);
}

// Round 6
// 225.926 us; speedup vs baseline: 1.0580x; 1.0580x over previous
//
#include <hip/hip_runtime.h>

// EMA chunked scan + inverse-gather broadcast for DeChunkLayer — 2 plain
// kernels (R6 = R4 verbatim resubmission; best measured at 226.1 us).
//
// Rationale: R1-R5 dur_us (233/235/226/239) tracks the harness poison-fill
// speed (6.5-6.7 TB/s run-to-run), not kernel structure. Timed window ~=
// ~190 us fixed harness traffic (512 MiB ws poison + out poison + input
// restore) + ~40 us kernel portion vs ~31 us traffic roofline. This round is
// a noise-control re-measurement of the best-known variant.
//
// x: (1, 16384, 1024) f32, p_selected: (16384,) f32, b: (1, 32768) i32
// out: (1, 32768, 1024) f32
// z_t = (1-p_t) z_{t-1} + p_t x_t  (p clipped to [1e-4, 1-1e-4])
// out[f] = z[t] for f in [pos[t], pos[t+1])
//
// K1: per-chunk local scan -> Bbuf/Abuf; per-segment b popcount -> bsum.
// K2: per-block redundant interchunk replay (<=511 serial steps off L2-resident
//     Bbuf) + rank-select of this chunk's 33 pos values + final scan + ranged
//     broadcast writes. All inter-block dataflow crosses ONE kernel boundary.

#define DCH 1024
#define L_COMP 16384
#define L_FULL 32768
#define CHUNK 32
#define NCHUNK (L_COMP / CHUNK)   // 512
#define SEG (L_FULL / NCHUNK)     // 64 b-elements per block
#define EPSV 1e-4f

__device__ __forceinline__ float clipp(float p) {
    p = fmaxf(p, EPSV);
    p = fminf(p, 1.0f - EPSV);
    return p;
}

// ---- K1: chunk-local scan (zero init) -> Bbuf[c], Abuf[c]; b segment sums
__global__ __launch_bounds__(256, 2) void chunk_kernel(
    const float* __restrict__ x, const float* __restrict__ p,
    const int* __restrict__ b,
    float* __restrict__ Bbuf, float* __restrict__ Abuf, int* __restrict__ bsum) {
    const int c = blockIdx.x;
    const int tid = threadIdx.x;
    const int lane = tid & 63;
    const int wave = tid >> 6;
    const int base = c * CHUNK;

    const float4* x4 = reinterpret_cast<const float4*>(x) + (size_t)c * CHUNK * (DCH / 4) + tid;
    float4 h = make_float4(0.f, 0.f, 0.f, 0.f);
    float aprod = 1.0f;
    for (int ib = 0; ib < CHUNK; ib += 8) {
        float4 xv[8];
        float pv[8];
#pragma unroll
        for (int j = 0; j < 8; ++j) {
            xv[j] = x4[(ib + j) * (DCH / 4)];
            pv[j] = clipp(p[base + ib + j]); // uniform -> scalar load
        }
#pragma unroll
        for (int j = 0; j < 8; ++j) {
            float a = 1.0f - pv[j];
            h.x = fmaf(a, h.x, pv[j] * xv[j].x);
            h.y = fmaf(a, h.y, pv[j] * xv[j].y);
            h.z = fmaf(a, h.z, pv[j] * xv[j].z);
            h.w = fmaf(a, h.w, pv[j] * xv[j].w);
            aprod *= a;
        }
    }
    reinterpret_cast<float4*>(Bbuf)[c * (DCH / 4) + tid] = h;
    if (tid == 0) Abuf[c] = aprod;
    if (wave == 0) {
        int v = b[c * SEG + lane];
        int s = v;
#pragma unroll
        for (int off = 1; off < 64; off <<= 1) s += __shfl_xor(s, off, 64);
        if (lane == 0) bsum[c] = s;
    }
}

// ---- K2: bpref scan + rank-select pos + redundant interchunk + final scan/write
__global__ __launch_bounds__(256, 2) void dechunk_kernel(
    const float* __restrict__ x, const float* __restrict__ p,
    const int* __restrict__ b, float* __restrict__ out,
    const float* __restrict__ Bbuf, const float* __restrict__ Abuf,
    const int* __restrict__ bsum) {
    const int c = blockIdx.x;
    const int tid = threadIdx.x;
    const int lane = tid & 63;
    const int wave = tid >> 6;
    const int base = c * CHUNK;

    __shared__ int bpref[NCHUNK + 1];
    __shared__ int spos[CHUNK + 1];
    __shared__ int wtot[4];

    // (a) block-local exclusive prefix over the 512 segment sums
    {
        int v0 = bsum[2 * tid];
        int v1 = bsum[2 * tid + 1];
        int s = v0 + v1;
        int incl = s;
#pragma unroll
        for (int off = 1; off < 64; off <<= 1) {
            int n = __shfl_up(incl, off, 64);
            if (lane >= off) incl += n;
        }
        if (lane == 63) wtot[wave] = incl;
        __syncthreads();
        int woff = 0;
        for (int w = 0; w < wave; ++w) woff += wtot[w];
        int ex = woff + incl - s; // exclusive prefix of this thread's pair
        bpref[2 * tid] = ex;
        bpref[2 * tid + 1] = ex + v0;
        if (tid == 0) bpref[NCHUNK] = L_COMP;
        __syncthreads();
    }

    // (b) rank-select this chunk's 33 pos values (threads 0..32)
    if (tid <= CHUNK) {
        int t = base + tid; // global one-rank (0-indexed)
        int posv = L_FULL;
        if (t < L_COMP) {
            int lo = 0, hi = NCHUNK;
            while (hi - lo > 1) {
                int mid = (lo + hi) >> 1;
                if (bpref[mid] <= t) lo = mid; else hi = mid;
            }
            int lr = t - bpref[lo]; // local rank within segment lo
            const int4* bseg = reinterpret_cast<const int4*>(b) + lo * (SEG / 4);
            int cnt = 0;
#pragma unroll 4
            for (int q = 0; q < SEG / 4; ++q) {
                int4 w = bseg[q];
                if (w.x) { if (cnt == lr) posv = lo * SEG + 4 * q + 0; ++cnt; }
                if (w.y) { if (cnt == lr) posv = lo * SEG + 4 * q + 1; ++cnt; }
                if (w.z) { if (cnt == lr) posv = lo * SEG + 4 * q + 2; ++cnt; }
                if (w.w) { if (cnt == lr) posv = lo * SEG + 4 * q + 3; ++cnt; }
            }
        }
        spos[tid] = posv;
    }

    // (c) redundant interchunk replay: h = state before chunk c (4 channels/thread)
    float4 h = make_float4(0.f, 0.f, 0.f, 0.f);
    {
        const float4* B4 = reinterpret_cast<const float4*>(Bbuf) + tid;
        int k = 0;
        for (; k + 16 <= c; k += 16) {
            float4 bv[16];
            float av[16];
#pragma unroll
            for (int j = 0; j < 16; ++j) {
                bv[j] = B4[(k + j) * (DCH / 4)];
                av[j] = Abuf[k + j]; // uniform -> scalar load
            }
#pragma unroll
            for (int j = 0; j < 16; ++j) {
                h.x = fmaf(av[j], h.x, bv[j].x);
                h.y = fmaf(av[j], h.y, bv[j].y);
                h.z = fmaf(av[j], h.z, bv[j].z);
                h.w = fmaf(av[j], h.w, bv[j].w);
            }
        }
        for (; k < c; ++k) {
            float4 bv = B4[k * (DCH / 4)];
            float a = Abuf[k];
            h.x = fmaf(a, h.x, bv.x);
            h.y = fmaf(a, h.y, bv.y);
            h.z = fmaf(a, h.z, bv.z);
            h.w = fmaf(a, h.w, bv.w);
        }
    }
    __syncthreads();

    // (d) final scan of chunk c with true init; broadcast-write output ranges
    {
        const float4* x4 = reinterpret_cast<const float4*>(x) + (size_t)c * CHUNK * (DCH / 4) + tid;
        float4* out4 = reinterpret_cast<float4*>(out) + tid;
        int f0 = spos[0];
        for (int ib = 0; ib < CHUNK; ib += 8) {
            float4 xv[8];
            float pv[8];
            int fe[8];
#pragma unroll
            for (int j = 0; j < 8; ++j) {
                xv[j] = x4[(ib + j) * (DCH / 4)];
                pv[j] = clipp(p[base + ib + j]); // uniform -> scalar
                fe[j] = spos[ib + j + 1];        // LDS
            }
#pragma unroll
            for (int j = 0; j < 8; ++j) {
                float a = 1.0f - pv[j];
                h.x = fmaf(a, h.x, pv[j] * xv[j].x);
                h.y = fmaf(a, h.y, pv[j] * xv[j].y);
                h.z = fmaf(a, h.z, pv[j] * xv[j].z);
                h.w = fmaf(a, h.w, pv[j] * xv[j].w);
                for (int f = f0; f < fe[j]; ++f) {
                    out4[(size_t)f * (DCH / 4)] = h;
                }
                f0 = fe[j];
            }
        }
    }
}

extern "C" void kernel_launch(void* const* d_in, const int* in_sizes, int n_in,
                              void* d_out, int out_size, void* d_ws, size_t ws_size,
                              hipStream_t stream) {
    const float* x = (const float*)d_in[0];
    const float* p = (const float*)d_in[1];
    const int* b = (const int*)d_in[2];
    float* out = (float*)d_out;

    char* ws = (char*)d_ws;
    float* Abuf = (float*)ws;                  // NCHUNK floats (2 KiB)
    int* bsum = (int*)(ws + 4096);             // NCHUNK ints (2 KiB)
    float* Bbuf = (float*)(ws + 8192);         // NCHUNK*DCH floats (2 MiB), 16B aligned

    chunk_kernel<<<NCHUNK, 256, 0, stream>>>(x, p, b, Bbuf, Abuf, bsum);
    dechunk_kernel<<<NCHUNK, 256, 0, stream>>>(x, p, b, out, Bbuf, Abuf, bsum);
}